// Round 6
// baseline (85.297 us; speedup 1.0000x reference)
//
#include <hip/hip_runtime.h>

#define B_ 32
#define T_ 4096
#define D_ 256
#define A_ 128

typedef __attribute__((ext_vector_type(8))) short bf16x8;
typedef __attribute__((ext_vector_type(4))) float f32x4;

__device__ __forceinline__ ushort f32_to_bf16_rne(float x) {
    uint u = __float_as_uint(x);
    u = (u + 0x7FFFu + ((u >> 16) & 1u)) >> 16;
    return (ushort)u;
}
__device__ __forceinline__ float bf16_bits_to_f32(ushort b) {
    return __uint_as_float(((uint)b) << 16);
}

// fast tanh: 1 - 2/(e^{2x}+1); exp overflow -> +-1 naturally.
__device__ __forceinline__ float fast_tanh(float x) {
    float t = __expf(2.0f * x);
    float r = __builtin_amdgcn_rcpf(t + 1.0f);
    return fmaf(-2.0f, r, 1.0f);
}

// split 8 f32 -> hi bf16x8 (round-half-up) + lo bf16x8 (residual)
__device__ __forceinline__ void split8(float4 a, float4 b, bf16x8& hi8, bf16x8& lo8) {
    float xs[8] = {a.x, a.y, a.z, a.w, b.x, b.y, b.z, b.w};
    union { uint w[4]; bf16x8 v; } H, L;
#pragma unroll
    for (int p = 0; p < 4; ++p) {
        float x0 = xs[2 * p], x1 = xs[2 * p + 1];
        uint r0 = __float_as_uint(x0) + 0x8000u;
        uint r1 = __float_as_uint(x1) + 0x8000u;
        H.w[p] = __builtin_amdgcn_perm(r1, r0, 0x07060302u);
        float rem0 = x0 - __uint_as_float(r0 & 0xFFFF0000u);
        float rem1 = x1 - __uint_as_float(r1 & 0xFFFF0000u);
        L.w[p] = __builtin_amdgcn_perm(__float_as_uint(rem1), __float_as_uint(rem0), 0x07060302u);
    }
    hi8 = H.v;
    lo8 = L.v;
}

// -----------------------------------------------------------------------------
// Kernel 0: W [A][D] fp32 -> hi/lo bf16 planes.
// -----------------------------------------------------------------------------
__global__ __launch_bounds__(256) void convert_W_kernel(
    const float* __restrict__ W, ushort* __restrict__ Whi, ushort* __restrict__ Wlo)
{
    const int i = blockIdx.x * 256 + threadIdx.x;
    float x = W[i];
    ushort hb = f32_to_bf16_rne(x);
    Whi[i] = hb;
    Wlo[i] = f32_to_bf16_rne(x - bf16_bits_to_f32(hb));
}

// -----------------------------------------------------------------------------
// Kernel 1 (fused): score + flash-style local-softmax pool. h read ONCE.
// Per wave: 16 rows. MFMA split-bf16 scores (W in LDS, 2 K-phases);
// epilogue computes wave-local (m_w, e_t, s_w) and unnormalized partial
// P_w[d] = sum_t e_t * h[t][d] from the RETAINED bf16 hi/lo fragments.
// Writes P_w (256 f32) + stats per wave. Block = 4 waves x 16 rows = 64 rows.
// -----------------------------------------------------------------------------
__global__ __launch_bounds__(256, 2) void score_pool_kernel(
    const float* __restrict__ h,
    const ushort* __restrict__ Whi, const ushort* __restrict__ Wlo,
    const float* __restrict__ bw, const float* __restrict__ uw,
    float* __restrict__ part, float2* __restrict__ stats)
{
    __shared__ char wlds[65536];   // [plane][row][swizzled 16B slot]
    __shared__ float sc[4][16];

    const int tid  = threadIdx.x;
    const int w    = tid >> 6;
    const int lane = tid & 63;
    const int l15  = lane & 15;
    const int l4   = lane >> 4;
    const int rowbase = blockIdx.x * 64 + w * 16;

    const float* hrow = h + (size_t)(rowbase + l15) * D_ + l4 * 8;

    f32x4 acc[8];
#pragma unroll
    for (int j = 0; j < 8; ++j)
#pragma unroll
        for (int r = 0; r < 4; ++r) acc[j][r] = 0.f;

    bf16x8 ahi[8], alo[8];   // retained for the pool phase (static indexing)
    float4 hbuf[8][2];       // ~3 slots live (full unroll)

#define PREF(s)                                                             \
    {                                                                       \
        hbuf[s][0] = *reinterpret_cast<const float4*>(hrow + (s) * 32);     \
        hbuf[s][1] = *reinterpret_cast<const float4*>(hrow + (s) * 32 + 4); \
    }

    PREF(0);
    PREF(1);

#pragma unroll
    for (int ph = 0; ph < 2; ++ph) {
        // ---- stage 64 KB of W (both planes, K-half ph) into LDS ----
#pragma unroll
        for (int p = 0; p < 2; ++p) {
            const ushort* src = p ? Wlo : Whi;
#pragma unroll
            for (int i = 0; i < 8; ++i) {
                const int c    = i * 256 + tid;
                const int row  = c >> 4;
                const int slot = c & 15;
                float4 v = *reinterpret_cast<const float4*>(
                    src + (size_t)row * D_ + ph * 128 + slot * 8);
                *reinterpret_cast<float4*>(
                    wlds + p * 32768 + row * 256 + ((slot ^ (row & 7)) << 4)) = v;
            }
        }
        __syncthreads();

#pragma unroll
        for (int st = 0; st < 4; ++st) {
            const int stg = ph * 4 + st;
            if (stg < 6) PREF(stg + 2);

            split8(hbuf[stg][0], hbuf[stg][1], ahi[stg], alo[stg]);

            const int slotbase = st * 4 + l4;
#pragma unroll
            for (int j = 0; j < 8; ++j) {
                const int row = j * 16 + l15;
                const int off = row * 256 + ((slotbase ^ (row & 7)) << 4);
                bf16x8 wh = *reinterpret_cast<const bf16x8*>(wlds + off);
                bf16x8 wl = *reinterpret_cast<const bf16x8*>(wlds + 32768 + off);
                acc[j] = __builtin_amdgcn_mfma_f32_16x16x32_bf16(ahi[stg], wh, acc[j], 0, 0, 0);
                acc[j] = __builtin_amdgcn_mfma_f32_16x16x32_bf16(alo[stg], wh, acc[j], 0, 0, 0);
                acc[j] = __builtin_amdgcn_mfma_f32_16x16x32_bf16(ahi[stg], wl, acc[j], 0, 0, 0);
            }
        }
        if (ph == 0) __syncthreads();
    }
#undef PREF

    // ---- scores for the wave's 16 rows ----
    float rsum[4] = {0.f, 0.f, 0.f, 0.f};
#pragma unroll
    for (int j = 0; j < 8; ++j) {
        const float bwv = bw[j * 16 + l15];
        const float uwv = uw[j * 16 + l15];
#pragma unroll
        for (int r = 0; r < 4; ++r)
            rsum[r] = fmaf(fast_tanh(acc[j][r] + bwv), uwv, rsum[r]);
    }
#pragma unroll
    for (int r = 0; r < 4; ++r) {
#pragma unroll
        for (int m = 1; m < 16; m <<= 1)
            rsum[r] += __shfl_xor(rsum[r], m, 64);
    }
    // D-frag: rsum[r] = score of local row l4*4+r. Publish so lane can fetch
    // the score of ITS h-row (l15).
    if (l15 == 0) {
#pragma unroll
        for (int r = 0; r < 4; ++r) sc[w][l4 * 4 + r] = rsum[r];
    }
    __syncthreads();

    const float scl = sc[w][l15];          // score of this lane's h-row
    float m_w = scl;
#pragma unroll
    for (int m = 1; m < 16; m <<= 1) m_w = fmaxf(m_w, __shfl_xor(m_w, m, 64));
    const float e = __expf(scl - m_w);     // unnormalized weight, <= 1
    float s_w = e;
#pragma unroll
    for (int m = 1; m < 16; m <<= 1) s_w += __shfl_xor(s_w, m, 64);

    const int wv = blockIdx.x * 4 + w;
    if (lane == 0) stats[wv] = make_float2(m_w, s_w);

    // ---- pool: P_w[d] = sum over 16 rows of e * h  (h = hi + lo, ~f32) ----
    float* pw = part + (size_t)wv * 256;
#pragma unroll
    for (int st = 0; st < 8; ++st) {
        float p[8];
#pragma unroll
        for (int i = 0; i < 8; ++i) {
            float hi = bf16_bits_to_f32((ushort)ahi[st][i]);
            float lo = bf16_bits_to_f32((ushort)alo[st][i]);
            p[i] = e * (hi + lo);
        }
#pragma unroll
        for (int m = 1; m < 16; m <<= 1) {
#pragma unroll
            for (int i = 0; i < 8; ++i) p[i] += __shfl_xor(p[i], m, 64);
        }
        if (l15 == 0) {
            float4 v0 = {p[0], p[1], p[2], p[3]};
            float4 v1 = {p[4], p[5], p[6], p[7]};
            *reinterpret_cast<float4*>(pw + st * 32 + l4 * 8)     = v0;
            *reinterpret_cast<float4*>(pw + st * 32 + l4 * 8 + 4) = v1;
        }
    }
}

// -----------------------------------------------------------------------------
// Kernel 2: per-batch flash combine. 256 wave-partials per batch.
// out[b][d] = (1/S) * sum_w exp(m_w - M) * P_w[d],
// M = max m_w, S = sum_w exp(m_w - M) * s_w.
// -----------------------------------------------------------------------------
__global__ __launch_bounds__(256) void batch_reduce_kernel(
    const float* __restrict__ part, const float2* __restrict__ stats,
    float* __restrict__ out)
{
    const int b = blockIdx.x;
    const int t = threadIdx.x;

    __shared__ float red[256];
    __shared__ float cw[256];

    const float2 stt = stats[b * 256 + t];
    red[t] = stt.x;
    __syncthreads();
    for (int s = 128; s > 0; s >>= 1) {
        if (t < s) red[t] = fmaxf(red[t], red[t + s]);
        __syncthreads();
    }
    const float M = red[0];
    __syncthreads();
    const float em = __expf(stt.x - M);
    red[t] = em * stt.y;
    __syncthreads();
    for (int s = 128; s > 0; s >>= 1) {
        if (t < s) red[t] += red[t + s];
        __syncthreads();
    }
    const float invS = 1.0f / red[0];
    cw[t] = em * invS;
    __syncthreads();

    float acc = 0.f;
    const float* pb = part + (size_t)b * 256 * 256 + t;
#pragma unroll 8
    for (int wv = 0; wv < 256; ++wv)
        acc = fmaf(cw[wv], pb[(size_t)wv * 256], acc);
    out[b * D_ + t] = acc;
}

extern "C" void kernel_launch(void* const* d_in, const int* in_sizes, int n_in,
                              void* d_out, int out_size, void* d_ws, size_t ws_size,
                              hipStream_t stream) {
    const float* h  = (const float*)d_in[0];
    const float* W  = (const float*)d_in[1];
    const float* bw = (const float*)d_in[2];
    const float* uw = (const float*)d_in[3];
    float* out = (float*)d_out;

    ushort* Whi   = (ushort*)d_ws;                        // 64 KB
    ushort* Wlo   = Whi + (size_t)A_ * D_;                // 64 KB
    float*  part  = (float*)(Wlo + (size_t)A_ * D_);      // 8192*256*4 = 8 MB
    float2* stats = (float2*)(part + (size_t)8192 * 256); // 64 KB

    convert_W_kernel<<<dim3((A_ * D_) / 256), 256, 0, stream>>>(W, Whi, Wlo);
    score_pool_kernel<<<dim3((B_ * T_) / 64), 256, 0, stream>>>(h, Whi, Wlo, bw, uw, part, stats);
    batch_reduce_kernel<<<dim3(B_), 256, 0, stream>>>(part, stats, out);
}

// Round 7
// 71.373 us; speedup vs baseline: 1.1951x; 1.1951x over previous
//
#include <hip/hip_runtime.h>

#define B_ 32
#define T_ 4096
#define D_ 256
#define A_ 128

typedef __attribute__((ext_vector_type(8))) short bf16x8;
typedef __attribute__((ext_vector_type(4))) float f32x4;

__device__ __forceinline__ ushort f32_to_bf16_rne(float x) {
    uint u = __float_as_uint(x);
    u = (u + 0x7FFFu + ((u >> 16) & 1u)) >> 16;
    return (ushort)u;
}
__device__ __forceinline__ float bf16_bits_to_f32(ushort b) {
    return __uint_as_float(((uint)b) << 16);
}

// fast tanh: 1 - 2/(e^{2x}+1); exp overflow -> +-1 naturally.
__device__ __forceinline__ float fast_tanh(float x) {
    float t = __expf(2.0f * x);
    float r = __builtin_amdgcn_rcpf(t + 1.0f);
    return fmaf(-2.0f, r, 1.0f);
}

// split 8 f32 -> hi bf16x8 (round-half-up) + lo bf16x8 (residual)
__device__ __forceinline__ void split8(float4 a, float4 b, bf16x8& hi8, bf16x8& lo8) {
    float xs[8] = {a.x, a.y, a.z, a.w, b.x, b.y, b.z, b.w};
    union { uint w[4]; bf16x8 v; } H, L;
#pragma unroll
    for (int p = 0; p < 4; ++p) {
        float x0 = xs[2 * p], x1 = xs[2 * p + 1];
        uint r0 = __float_as_uint(x0) + 0x8000u;
        uint r1 = __float_as_uint(x1) + 0x8000u;
        H.w[p] = __builtin_amdgcn_perm(r1, r0, 0x07060302u);
        float rem0 = x0 - __uint_as_float(r0 & 0xFFFF0000u);
        float rem1 = x1 - __uint_as_float(r1 & 0xFFFF0000u);
        L.w[p] = __builtin_amdgcn_perm(__float_as_uint(rem1), __float_as_uint(rem0), 0x07060302u);
    }
    hi8 = H.v;
    lo8 = L.v;
}

// -----------------------------------------------------------------------------
// Kernel 0: W [A][D] fp32 -> hi/lo bf16 planes.
// -----------------------------------------------------------------------------
__global__ __launch_bounds__(256) void convert_W_kernel(
    const float* __restrict__ W, ushort* __restrict__ Whi, ushort* __restrict__ Wlo)
{
    const int i = blockIdx.x * 256 + threadIdx.x;
    float x = W[i];
    ushort hb = f32_to_bf16_rne(x);
    Whi[i] = hb;
    Wlo[i] = f32_to_bf16_rne(x - bf16_bits_to_f32(hb));
}

// -----------------------------------------------------------------------------
// Kernel 1: score = sum_a tanh(h·W^T + bw)·uw  via split-bf16 MFMA.
// - W lives in LDS (lgkmcnt) so vmcnt carries only the h stream.
// - W staged in FOUR 32KB K-phases (k-chunks of 64) -> 3 blocks/CU.
// - ALL 8 h-stages prefetched upfront (64 VGPR): the h stream is issued once,
//   before any W staging, so no mid-loop wait can hurt it.
// LDS: [plane][row 0..127][slot 0..7 of 16B], slot ^= (row&7) swizzle.
// Block = 4 waves x 16 rows = 64 rows; grid 2048.
// -----------------------------------------------------------------------------
__global__ __launch_bounds__(256, 3) void score_mfma_kernel(
    const float* __restrict__ h,
    const ushort* __restrict__ Whi, const ushort* __restrict__ Wlo,
    const float* __restrict__ bw, const float* __restrict__ uw,
    float* __restrict__ score)
{
    __shared__ char wlds[32768];

    const int tid  = threadIdx.x;
    const int w    = tid >> 6;
    const int lane = tid & 63;
    const int l15  = lane & 15;
    const int l4   = lane >> 4;
    const int rowbase = blockIdx.x * 64 + w * 16;

    const float* hrow = h + (size_t)(rowbase + l15) * D_ + l4 * 8;

    // ---- issue the ENTIRE h stream upfront ----
    float4 hbuf[8][2];
#pragma unroll
    for (int s = 0; s < 8; ++s) {
        hbuf[s][0] = *reinterpret_cast<const float4*>(hrow + s * 32);
        hbuf[s][1] = *reinterpret_cast<const float4*>(hrow + s * 32 + 4);
    }

    f32x4 acc[8];
#pragma unroll
    for (int j = 0; j < 8; ++j)
#pragma unroll
        for (int r = 0; r < 4; ++r) acc[j][r] = 0.f;

#pragma unroll
    for (int ph = 0; ph < 4; ++ph) {
        // ---- stage 32 KB of W (both planes, k-chunk ph*64..+64) ----
#pragma unroll
        for (int i = 0; i < 8; ++i) {
            const int c    = i * 256 + tid;      // 0..2047 16B-chunks
            const int p    = c >> 10;            // plane
            const int rem  = c & 1023;
            const int row  = rem >> 3;           // 0..127
            const int slot = rem & 7;            // 0..7
            const ushort* src = (p ? Wlo : Whi) + (size_t)row * D_ + ph * 64 + slot * 8;
            float4 v = *reinterpret_cast<const float4*>(src);
            *reinterpret_cast<float4*>(
                wlds + p * 16384 + row * 128 + ((slot ^ (row & 7)) << 4)) = v;
        }
        __syncthreads();

#pragma unroll
        for (int st = 0; st < 2; ++st) {
            const int stg = ph * 2 + st;
            bf16x8 ahi, alo;
            split8(hbuf[stg][0], hbuf[stg][1], ahi, alo);

            const int slotbase = st * 4 + l4;
#pragma unroll
            for (int j = 0; j < 8; ++j) {
                const int row = j * 16 + l15;
                const int off = row * 128 + ((slotbase ^ (row & 7)) << 4);
                bf16x8 wh = *reinterpret_cast<const bf16x8*>(wlds + off);
                bf16x8 wl = *reinterpret_cast<const bf16x8*>(wlds + 16384 + off);
                acc[j] = __builtin_amdgcn_mfma_f32_16x16x32_bf16(ahi, wh, acc[j], 0, 0, 0);
                acc[j] = __builtin_amdgcn_mfma_f32_16x16x32_bf16(alo, wh, acc[j], 0, 0, 0);
                acc[j] = __builtin_amdgcn_mfma_f32_16x16x32_bf16(ahi, wl, acc[j], 0, 0, 0);
            }
        }
        if (ph < 3) __syncthreads();
    }

    // ---- epilogue: tanh + dot(uw) + 16-lane reduce ----
    float rsum[4] = {0.f, 0.f, 0.f, 0.f};
#pragma unroll
    for (int j = 0; j < 8; ++j) {
        const float bwv = bw[j * 16 + l15];
        const float uwv = uw[j * 16 + l15];
#pragma unroll
        for (int r = 0; r < 4; ++r)
            rsum[r] = fmaf(fast_tanh(acc[j][r] + bwv), uwv, rsum[r]);
    }
#pragma unroll
    for (int r = 0; r < 4; ++r) {
#pragma unroll
        for (int m = 1; m < 16; m <<= 1)
            rsum[r] += __shfl_xor(rsum[r], m, 64);
    }
    if (l15 == 0) {
#pragma unroll
        for (int r = 0; r < 4; ++r)
            score[rowbase + l4 * 4 + r] = rsum[r];
    }
}

// -----------------------------------------------------------------------------
// Kernel 2: flash-style pool. Block (c,b) owns 64 t-rows: computes local
// m_c, e_t = exp(s_t - m_c), s_c, and P_c[d] = sum_t e_t*h[t][d].
// Writes P_c (256 f32) + (m_c, s_c). Raw scores in, no global softmax pass.
// -----------------------------------------------------------------------------
__global__ __launch_bounds__(256) void pool_flash_kernel(
    const float* __restrict__ h, const float* __restrict__ score,
    float* __restrict__ part, float2* __restrict__ stats)
{
    const int b  = blockIdx.y;
    const int c  = blockIdx.x;
    const int d4 = threadIdx.x & 63;
    const int tr = threadIdx.x >> 6;

    __shared__ float sld[64];
    __shared__ float elds[64];
    __shared__ float4 red[4][64];

    if (threadIdx.x < 64)
        sld[threadIdx.x] = score[(size_t)b * T_ + c * 64 + threadIdx.x];
    __syncthreads();

    float m_c = -3.0e38f;
#pragma unroll
    for (int t = 0; t < 64; ++t) m_c = fmaxf(m_c, sld[t]);   // broadcast reads

    if (threadIdx.x < 64) {
        float e = __expf(sld[threadIdx.x] - m_c);
        elds[threadIdx.x] = e;
        float s = e;
#pragma unroll
        for (int msk = 1; msk < 64; msk <<= 1) s += __shfl_xor(s, msk, 64);
        if (threadIdx.x == 0)
            stats[b * 64 + c] = make_float2(m_c, s);
    }
    __syncthreads();

    const float* hp = h + ((size_t)b * T_ + (size_t)c * 64) * D_;
    float4 acc = {0.f, 0.f, 0.f, 0.f};
#pragma unroll
    for (int i = 0; i < 16; ++i) {
        const int r = i * 4 + tr;
        float4 v = *reinterpret_cast<const float4*>(hp + (size_t)r * D_ + d4 * 4);
        const float e = elds[r];
        acc.x = fmaf(e, v.x, acc.x);
        acc.y = fmaf(e, v.y, acc.y);
        acc.z = fmaf(e, v.z, acc.z);
        acc.w = fmaf(e, v.w, acc.w);
    }
    red[tr][d4] = acc;
    __syncthreads();
    if (tr == 0) {
        float4 s0 = red[0][d4], s1 = red[1][d4], s2 = red[2][d4], s3 = red[3][d4];
        float4 o = {s0.x + s1.x + s2.x + s3.x, s0.y + s1.y + s2.y + s3.y,
                    s0.z + s1.z + s2.z + s3.z, s0.w + s1.w + s2.w + s3.w};
        *reinterpret_cast<float4*>(part + ((size_t)b * 64 + c) * D_ + d4 * 4) = o;
    }
}

// -----------------------------------------------------------------------------
// Kernel 3: exact flash combine per batch over 64 chunk-partials.
// out[b][d] = sum_c exp(m_c-M)*P_c[d] / sum_c exp(m_c-M)*s_c,  M = max_c m_c.
// -----------------------------------------------------------------------------
__global__ __launch_bounds__(256) void combine_kernel(
    const float* __restrict__ part, const float2* __restrict__ stats,
    float* __restrict__ out)
{
    const int b = blockIdx.x;
    const int t = threadIdx.x;

    __shared__ float cw[64];

    if (t < 64) {   // first wave
        const float2 st = stats[b * 64 + t];
        float M = st.x;
#pragma unroll
        for (int msk = 1; msk < 64; msk <<= 1) M = fmaxf(M, __shfl_xor(M, msk, 64));
        const float em = __expf(st.x - M);
        float S = em * st.y;
#pragma unroll
        for (int msk = 1; msk < 64; msk <<= 1) S += __shfl_xor(S, msk, 64);
        cw[t] = em / S;
    }
    __syncthreads();

    float acc = 0.f;
    const float* pb = part + (size_t)b * 64 * 256 + t;
#pragma unroll 8
    for (int c = 0; c < 64; ++c)
        acc = fmaf(cw[c], pb[(size_t)c * 256], acc);
    out[b * D_ + t] = acc;
}

extern "C" void kernel_launch(void* const* d_in, const int* in_sizes, int n_in,
                              void* d_out, int out_size, void* d_ws, size_t ws_size,
                              hipStream_t stream) {
    const float* h  = (const float*)d_in[0];
    const float* W  = (const float*)d_in[1];
    const float* bw = (const float*)d_in[2];
    const float* uw = (const float*)d_in[3];
    float* out = (float*)d_out;

    float*  score = (float*)d_ws;                         // 512 KB
    ushort* Whi   = (ushort*)(score + (size_t)B_ * T_);   // 64 KB
    ushort* Wlo   = Whi + (size_t)A_ * D_;                // 64 KB
    float*  part  = (float*)(Wlo + (size_t)A_ * D_);      // 32*64*256*4 = 2 MB
    float2* stats = (float2*)(part + (size_t)B_ * 64 * D_); // 16 KB

    convert_W_kernel<<<dim3((A_ * D_) / 256), 256, 0, stream>>>(W, Whi, Wlo);
    score_mfma_kernel<<<dim3((B_ * T_) / 64), 256, 0, stream>>>(h, Whi, Wlo, bw, uw, score);
    pool_flash_kernel<<<dim3(64, B_), 256, 0, stream>>>(h, score, part, stats);
    combine_kernel<<<dim3(B_), 256, 0, stream>>>(part, stats, out);
}

// Round 8
// 62.965 us; speedup vs baseline: 1.3547x; 1.1335x over previous
//
#include <hip/hip_runtime.h>

#define B_ 32
#define T_ 4096
#define D_ 256
#define A_ 128

typedef __attribute__((ext_vector_type(8))) short bf16x8;
typedef __attribute__((ext_vector_type(4))) float f32x4;

__device__ __forceinline__ ushort f32_to_bf16_rne(float x) {
    uint u = __float_as_uint(x);
    u = (u + 0x7FFFu + ((u >> 16) & 1u)) >> 16;
    return (ushort)u;
}
__device__ __forceinline__ float bf16_bits_to_f32(ushort b) {
    return __uint_as_float(((uint)b) << 16);
}

// fast tanh: 1 - 2/(e^{2x}+1); exp overflow -> +-1 naturally.
__device__ __forceinline__ float fast_tanh(float x) {
    float t = __expf(2.0f * x);
    float r = __builtin_amdgcn_rcpf(t + 1.0f);
    return fmaf(-2.0f, r, 1.0f);
}

// split 8 f32 -> hi bf16x8 (round-half-up) + lo bf16x8 (residual)
__device__ __forceinline__ void split8(float4 a, float4 b, bf16x8& hi8, bf16x8& lo8) {
    float xs[8] = {a.x, a.y, a.z, a.w, b.x, b.y, b.z, b.w};
    union { uint w[4]; bf16x8 v; } H, L;
#pragma unroll
    for (int p = 0; p < 4; ++p) {
        float x0 = xs[2 * p], x1 = xs[2 * p + 1];
        uint r0 = __float_as_uint(x0) + 0x8000u;
        uint r1 = __float_as_uint(x1) + 0x8000u;
        H.w[p] = __builtin_amdgcn_perm(r1, r0, 0x07060302u);
        float rem0 = x0 - __uint_as_float(r0 & 0xFFFF0000u);
        float rem1 = x1 - __uint_as_float(r1 & 0xFFFF0000u);
        L.w[p] = __builtin_amdgcn_perm(__float_as_uint(rem1), __float_as_uint(rem0), 0x07060302u);
    }
    hi8 = H.v;
    lo8 = L.v;
}

// -----------------------------------------------------------------------------
// Kernel 0: W [A][D] fp32 -> hi/lo bf16 planes.
// -----------------------------------------------------------------------------
__global__ __launch_bounds__(256) void convert_W_kernel(
    const float* __restrict__ W, ushort* __restrict__ Whi, ushort* __restrict__ Wlo)
{
    const int i = blockIdx.x * 256 + threadIdx.x;
    float x = W[i];
    ushort hb = f32_to_bf16_rne(x);
    Whi[i] = hb;
    Wlo[i] = f32_to_bf16_rne(x - bf16_bits_to_f32(hb));
}

// -----------------------------------------------------------------------------
// Kernel 1 (fused): score (split-bf16 MFMA, W in LDS, 4x32KB K-phases,
// upfront h burst) + flash-local pool via L2-hot re-read of the block's own
// 64 rows. NO register retention across the MFMA loop (R6 lesson).
// Block = 4 waves x 16 rows = 64 rows = one flash chunk; grid 2048.
// Writes P_c[256] + (m_c, s_c) per chunk.
// -----------------------------------------------------------------------------
__global__ __launch_bounds__(256, 3) void score_pool_kernel(
    const float* __restrict__ h,
    const ushort* __restrict__ Whi, const ushort* __restrict__ Wlo,
    const float* __restrict__ bw, const float* __restrict__ uw,
    float* __restrict__ part, float2* __restrict__ stats)
{
    __shared__ char wlds[32768];
    __shared__ float sc64[64];
    __shared__ float elds[64];
    __shared__ float4 redp[4][64];

    const int tid  = threadIdx.x;
    const int w    = tid >> 6;
    const int lane = tid & 63;
    const int l15  = lane & 15;
    const int l4   = lane >> 4;
    const int rowbase = blockIdx.x * 64 + w * 16;

    const float* hrow = h + (size_t)(rowbase + l15) * D_ + l4 * 8;

    // ---- issue the ENTIRE h stream upfront (oldest in vmcnt queue) ----
    float4 hbuf[8][2];
#pragma unroll
    for (int s = 0; s < 8; ++s) {
        hbuf[s][0] = *reinterpret_cast<const float4*>(hrow + s * 32);
        hbuf[s][1] = *reinterpret_cast<const float4*>(hrow + s * 32 + 4);
    }

    f32x4 acc[8];
#pragma unroll
    for (int j = 0; j < 8; ++j)
#pragma unroll
        for (int r = 0; r < 4; ++r) acc[j][r] = 0.f;

#pragma unroll
    for (int ph = 0; ph < 4; ++ph) {
        // ---- stage 32 KB of W (both planes, k-chunk ph*64..+64) ----
#pragma unroll
        for (int i = 0; i < 8; ++i) {
            const int c    = i * 256 + tid;      // 0..2047 16B-chunks
            const int p    = c >> 10;            // plane
            const int rem  = c & 1023;
            const int row  = rem >> 3;           // 0..127
            const int slot = rem & 7;            // 0..7
            const ushort* src = (p ? Wlo : Whi) + (size_t)row * D_ + ph * 64 + slot * 8;
            float4 v = *reinterpret_cast<const float4*>(src);
            *reinterpret_cast<float4*>(
                wlds + p * 16384 + row * 128 + ((slot ^ (row & 7)) << 4)) = v;
        }
        __syncthreads();

#pragma unroll
        for (int st = 0; st < 2; ++st) {
            const int stg = ph * 2 + st;
            bf16x8 ahi, alo;
            split8(hbuf[stg][0], hbuf[stg][1], ahi, alo);

            const int slotbase = st * 4 + l4;
#pragma unroll
            for (int j = 0; j < 8; ++j) {
                const int row = j * 16 + l15;
                const int off = row * 128 + ((slotbase ^ (row & 7)) << 4);
                bf16x8 wh = *reinterpret_cast<const bf16x8*>(wlds + off);
                bf16x8 wl = *reinterpret_cast<const bf16x8*>(wlds + 16384 + off);
                acc[j] = __builtin_amdgcn_mfma_f32_16x16x32_bf16(ahi, wh, acc[j], 0, 0, 0);
                acc[j] = __builtin_amdgcn_mfma_f32_16x16x32_bf16(alo, wh, acc[j], 0, 0, 0);
                acc[j] = __builtin_amdgcn_mfma_f32_16x16x32_bf16(ahi, wl, acc[j], 0, 0, 0);
            }
        }
        __syncthreads();
    }

    // ---- scores ----
    float rsum[4] = {0.f, 0.f, 0.f, 0.f};
#pragma unroll
    for (int j = 0; j < 8; ++j) {
        const float bwv = bw[j * 16 + l15];
        const float uwv = uw[j * 16 + l15];
#pragma unroll
        for (int r = 0; r < 4; ++r)
            rsum[r] = fmaf(fast_tanh(acc[j][r] + bwv), uwv, rsum[r]);
    }
#pragma unroll
    for (int r = 0; r < 4; ++r) {
#pragma unroll
        for (int m = 1; m < 16; m <<= 1)
            rsum[r] += __shfl_xor(rsum[r], m, 64);
    }
    if (l15 == 0) {
#pragma unroll
        for (int r = 0; r < 4; ++r)
            sc64[w * 16 + l4 * 4 + r] = rsum[r];
    }
    __syncthreads();

    // ---- flash-local softmax over the block's 64 rows ----
    float m_c = -3.0e38f;
#pragma unroll
    for (int t = 0; t < 64; ++t) m_c = fmaxf(m_c, sc64[t]);   // LDS broadcast

    if (tid < 64) {
        float e = __expf(sc64[tid] - m_c);
        elds[tid] = e;
        float s = e;
#pragma unroll
        for (int msk = 1; msk < 64; msk <<= 1) s += __shfl_xor(s, msk, 64);
        if (tid == 0) stats[blockIdx.x] = make_float2(m_c, s);
    }
    __syncthreads();

    // ---- pool: P_c[d] = sum_t e_t * h[t][d], h re-read (L2-hot) ----
    const int d4 = tid & 63;
    const int tr = tid >> 6;
    const float* hp = h + (size_t)blockIdx.x * 64 * D_;
    float4 pacc = {0.f, 0.f, 0.f, 0.f};
#pragma unroll
    for (int i = 0; i < 16; ++i) {
        const int r = i * 4 + tr;
        float4 v = *reinterpret_cast<const float4*>(hp + (size_t)r * D_ + d4 * 4);
        const float e = elds[r];
        pacc.x = fmaf(e, v.x, pacc.x);
        pacc.y = fmaf(e, v.y, pacc.y);
        pacc.z = fmaf(e, v.z, pacc.z);
        pacc.w = fmaf(e, v.w, pacc.w);
    }
    redp[tr][d4] = pacc;
    __syncthreads();
    if (tr == 0) {
        float4 s0 = redp[0][d4], s1 = redp[1][d4], s2 = redp[2][d4], s3 = redp[3][d4];
        float4 o = {s0.x + s1.x + s2.x + s3.x, s0.y + s1.y + s2.y + s3.y,
                    s0.z + s1.z + s2.z + s3.z, s0.w + s1.w + s2.w + s3.w};
        *reinterpret_cast<float4*>(part + (size_t)blockIdx.x * D_ + d4 * 4) = o;
    }
}

// -----------------------------------------------------------------------------
// Kernel 2: exact flash combine per batch over its 64 chunk-partials.
// out[b][d] = sum_c exp(m_c-M)*P_c[d] / sum_c exp(m_c-M)*s_c,  M = max_c m_c.
// -----------------------------------------------------------------------------
__global__ __launch_bounds__(256) void combine_kernel(
    const float* __restrict__ part, const float2* __restrict__ stats,
    float* __restrict__ out)
{
    const int b = blockIdx.x;
    const int t = threadIdx.x;

    __shared__ float cw[64];

    if (t < 64) {
        const float2 st = stats[b * 64 + t];
        float M = st.x;
#pragma unroll
        for (int msk = 1; msk < 64; msk <<= 1) M = fmaxf(M, __shfl_xor(M, msk, 64));
        const float em = __expf(st.x - M);
        float S = em * st.y;
#pragma unroll
        for (int msk = 1; msk < 64; msk <<= 1) S += __shfl_xor(S, msk, 64);
        cw[t] = em / S;
    }
    __syncthreads();

    float acc = 0.f;
    const float* pb = part + (size_t)b * 64 * 256 + t;
#pragma unroll 8
    for (int c = 0; c < 64; ++c)
        acc = fmaf(cw[c], pb[(size_t)c * 256], acc);
    out[b * D_ + t] = acc;
}

extern "C" void kernel_launch(void* const* d_in, const int* in_sizes, int n_in,
                              void* d_out, int out_size, void* d_ws, size_t ws_size,
                              hipStream_t stream) {
    const float* h  = (const float*)d_in[0];
    const float* W  = (const float*)d_in[1];
    const float* bw = (const float*)d_in[2];
    const float* uw = (const float*)d_in[3];
    float* out = (float*)d_out;

    ushort* Whi   = (ushort*)d_ws;                          // 64 KB
    ushort* Wlo   = Whi + (size_t)A_ * D_;                  // 64 KB
    float*  part  = (float*)(Wlo + (size_t)A_ * D_);        // 2048*256*4 = 2 MB
    float2* stats = (float2*)(part + (size_t)2048 * D_);    // 16 KB

    convert_W_kernel<<<dim3((A_ * D_) / 256), 256, 0, stream>>>(W, Whi, Wlo);
    score_pool_kernel<<<dim3((B_ * T_) / 64), 256, 0, stream>>>(h, Whi, Wlo, bw, uw, part, stats);
    combine_kernel<<<dim3(B_), 256, 0, stream>>>(part, stats, out);
}